// Round 2
// baseline (129.216 us; speedup 1.0000x reference)
//
#include <hip/hip_runtime.h>

// SIAF forward. Round 9: fuse prep into the main kernel.
// Round-8 lesson: the 256 MiB workspace re-poison (~43 us fillBufferAligned) is
// UNCONDITIONAL -- it runs whether or not we touch d_ws, so it is a fixed
// harness floor. Remaining controllable time = siaf_prep (~2 us) + launch
// bubble (~2 us) + siaf_main (~20 us vs ~13 us compute/memory floor).
// This round: each block builds the 56 KB weight image in LDS directly from
// the raw global weights (same per-element math as the old prep kernel),
// eliminating the prep dispatch, the inter-kernel serialization bubble, and
// the g_ws round trip. x-stage global loads are issued BEFORE prep VALU work
// and B-frag packing (own-wave LDS, no barrier needed) runs before the single
// __syncthreads, so global latency hides under prep compute.
//
// Round 7 recap (compute path unchanged, verified absmax 0.0625):
// GEMM1 = permuted-row MFMA 16x16x32 bf16 (lane owns the full 8-wide hidden
// vector of layer l=4w+quad); GEMM2 = 16 fp32 FMAs against broadcast LDS
// reads. 1024-thread blocks (16 waves x 16 samples), dynamic LDS 119 KB ->
// 1 block/CU, 4 waves/SIMD. Rounds 4-6 lesson: compiler won't hold VMEM
// weight prefetches in registers; LDS staging is the structural fix.

#define DIMS 64
#define TPB  1024
#define WAVES 16
#define SPW  16

typedef __attribute__((ext_vector_type(8))) short short8;
typedef __attribute__((ext_vector_type(4))) float f32x4;
typedef __attribute__((ext_vector_type(4))) unsigned int uint4v;
typedef unsigned short ushort_t;
typedef unsigned int uint_t;

#if __has_builtin(__builtin_amdgcn_exp2f)
#define YSCALE 2.8853900817779268f      /* 2*log2(e): exp(2y) = exp2(YSCALE*y) */
#define EXPY(x) __builtin_amdgcn_exp2f(x)
#else
#define YSCALE 2.0f
#define EXPY(x) __expf(x)
#endif

// LDS weight-image layout (bytes):
//  A [0,16384):      w1 rows 0..255 (l<32), 64 B/row (k<32 only), 4-chunk XOR swizzle
//  B [16384,49152):  w1 rows 256..511, 128 B/row, 8-chunk XOR swizzle
//  C [49152,53248):  W2 fp32 [64 l][2 o][8 h]
//  D [53248,55296):  b1 fp32 [512] in physical (permuted) row order, YSCALE-scaled
//  E [55296,55808):  b2 fp32 [64][2]
#define A_OFF 0
#define B_OFF 16384
#define C_OFF 49152
#define D_OFF 53248
#define E_OFF 55296
#define WT_BYTES 55808
#define XZ_OFF WT_BYTES
#define LDS_BYTES (WT_BYTES + WAVES * SPW * DIMS * 4)   // 55808 + 65536 = 121344
#define PREP_N (24576 + 1664)

__device__ __forceinline__ uint_t pk2bf(float a, float b) {
#if __has_builtin(__builtin_amdgcn_cvt_pk_bf16_f32)
    typedef __attribute__((ext_vector_type(2))) __bf16 bf16x2;
    bf16x2 r = __builtin_amdgcn_cvt_pk_bf16_f32(a, b);
    return __builtin_bit_cast(uint_t, r);
#else
    uint_t ua = __float_as_uint(a); ua += 0x7FFFu + ((ua >> 16) & 1u);
    uint_t ub = __float_as_uint(b); ub += 0x7FFFu + ((ub >> 16) & 1u);
    return (ub & 0xFFFF0000u) | (ua >> 16);
#endif
}

__device__ __forceinline__ ushort_t f2bf(float f) {
    uint_t u = __float_as_uint(f);
    u += 0x7FFFu + ((u >> 16) & 1u);
    return (ushort_t)(u >> 16);
}

// logical row L for physical GEMM1 row p (window w=p>>5, tile parity e=(p>>4)&1,
// n=p&15): L = w*32 + (n>>2)*8 + e*4 + (n&3);  l = L>>3, h = L&7.
__device__ __forceinline__ int logrow(int p) {
    int n = p & 15;
    return (p >> 5) * 32 + (n >> 2) * 8 + ((p >> 4) & 1) * 4 + (n & 3);
}

__device__ __forceinline__ float th(float t) {
    // t = YSCALE*y ; tanh(y) = 1 - 2/(exp2(t)+1)
    float e = EXPY(t);
    float r = __builtin_amdgcn_rcpf(e + 1.0f);
    return fmaf(-2.0f, r, 1.0f);
}

__global__ __launch_bounds__(TPB, 4) void siaf_main(
        const float* __restrict__ x, const float* __restrict__ ip,
        const float* __restrict__ W1, const float* __restrict__ b1,
        const float* __restrict__ W2, const float* __restrict__ b2,
        float* __restrict__ out, int nB) {
    extern __shared__ unsigned char lds[];

    const int tid  = threadIdx.x;
    const int wv   = tid >> 6, lane = tid & 63;
    const int s16  = lane & 15, quad = lane >> 4;
    const int sbase = blockIdx.x * (WAVES * SPW) + wv * SPW;
    float* xzw = (float*)(lds + XZ_OFF) + wv * (SPW * DIMS);

    // ---- stage x FIRST: coalesced 1KB/instr, 16B-chunk XOR swizzle (key=row).
    // Issued before weight prep so the global-load latency hides under the
    // prep VALU/convert work below. Own-wave LDS region: no barrier needed.
    #pragma unroll
    for (int g = 0; g < 4; ++g) {
        const float4 v = ((const float4*)(x + (size_t)sbase * DIMS))[g * 64 + lane];
        const int s_loc = 4 * g + quad;
        const int pc = (s16 ^ s_loc) & 15;
        *(float4*)(xzw + s_loc * 64 + pc * 4) = v;
    }
    const float ip0 = ip[0], ip1 = ip[1];

    // ---- build the 56 KB weight image in LDS directly from global weights.
    // Same per-element arithmetic as the (verified) standalone prep kernel;
    // all blocks build the identical image. Weights are ~130 KB -> L2-resident
    // after the first block per XCD. 26 strided iterations, branch-uniform
    // across the block (24576 = 24*TPB exactly).
    {
        ushort_t* __restrict__ wsu = (ushort_t*)lds;
        float* __restrict__ fws = (float*)(lds + C_OFF);
        for (int i = tid; i < PREP_N; i += TPB) {
            if (i < 8192) {                       // region A: p<256, 32 ushorts/row
                int p = i >> 5, e = i & 31;
                int cp = e >> 3, j = e & 7;
                int k = ((cp ^ (p & 3)) << 3) | j;      // de-swizzled logical k (<32)
                int L = logrow(p), l = L >> 3, h = L & 7;
                float v = (k <= l) ? W1[(l * 8 + h) * 63 + k] * YSCALE : 0.0f;
                wsu[i] = f2bf(v);
            } else if (i < 24576) {               // region B: p in [256,512), 64 ushorts/row
                int v_ = i - 8192;
                int p = 256 + (v_ >> 6), e = v_ & 63;
                int cp = e >> 3, j = e & 7;
                int k = ((cp ^ (p & 7)) << 3) | j;
                int L = logrow(p), l = L >> 3, h = L & 7;
                float v = (l < 63 && k <= l) ? W1[(l * 8 + h) * 63 + k] * YSCALE : 0.0f;
                wsu[i] = f2bf(v);
            } else {                              // fp32 regions C/D/E
                int f = i - 24576;
                float v = 0.0f;
                if (f < 1024) {                   // C: W2 [l][o][h]
                    int l = f >> 4, o = (f >> 3) & 1, h = f & 7;
                    if (l < 63) v = W2[(l * 2 + o) * 8 + h];
                } else if (f < 1536) {            // D: b1 in physical row order
                    int p = f - 1024;
                    int L = logrow(p), l = L >> 3, h = L & 7;
                    if (l < 63) v = b1[l * 8 + h] * YSCALE;
                } else {                          // E: b2 [l][o]
                    int j = f - 1536, l = j >> 1, o = j & 1;
                    if (l < 63) v = b2[l * 2 + o];
                }
                fws[f] = v;
            }
        }
    }

    // ---- B-frag: B[k=quad*8+j][n=s16] from own-wave LDS region, bf16.
    // Reads only what this wave wrote above -> safe before the barrier.
    short8 bfr[2];
    #pragma unroll
    for (int kh = 0; kh < 2; ++kh) {
        const int c0 = kh * 8 + quad * 2;
        float4 va = *(const float4*)(xzw + s16 * 64 + ((c0 ^ s16) & 15) * 4);
        float4 vb = *(const float4*)(xzw + s16 * 64 + (((c0 + 1) ^ s16) & 15) * 4);
        uint4v u = {pk2bf(va.x, va.y), pk2bf(va.z, va.w),
                    pk2bf(vb.x, vb.y), pk2bf(vb.z, vb.w)};
        bfr[kh] = __builtin_bit_cast(short8, u);
    }

    __syncthreads();   // weight image ready for all waves

    const ushort_t* wA  = (const ushort_t*)(lds + A_OFF);
    const ushort_t* wB  = (const ushort_t*)(lds + B_OFF);
    const float*    w2f = (const float*)(lds + C_OFF);
    const float*    b1f = (const float*)(lds + D_OFF);
    const float*    b2f = (const float*)(lds + E_OFF);

    float lsum = 0.0f;
    #pragma unroll
    for (int w = 0; w < 16; ++w) {
        // A-frags from LDS (bank-balanced XOR-swizzled rows)
        short8 a00, a10, a01{}, a11{};
        if (w < 8) {
            const ushort_t* base = wA + (w * 32 + s16) * 32;   // 64 B rows
            const int pc = quad ^ (s16 & 3);
            a00 = *(const short8*)(base + pc * 8);
            a10 = *(const short8*)(base + 512 + pc * 8);       // +16 rows
        } else {
            const ushort_t* base = wB + ((w - 8) * 32 + s16) * 64;  // 128 B rows
            const int pc = quad ^ (s16 & 7);
            a00 = *(const short8*)(base + pc * 8);
            a10 = *(const short8*)(base + 1024 + pc * 8);
            a01 = *(const short8*)(base + (pc ^ 4) * 8);
            a11 = *(const short8*)(base + 1024 + (pc ^ 4) * 8);
        }
        const float4 bi0 = *(const float4*)(b1f + w * 32 + quad * 4);       // broadcast
        const float4 bi1 = *(const float4*)(b1f + w * 32 + 16 + quad * 4);  // broadcast

        f32x4 aE = {bi0.x, bi0.y, bi0.z, bi0.w};
        f32x4 aO = {bi1.x, bi1.y, bi1.z, bi1.w};
        aE = __builtin_amdgcn_mfma_f32_16x16x32_bf16(a00, bfr[0], aE, 0, 0, 0);
        aO = __builtin_amdgcn_mfma_f32_16x16x32_bf16(a10, bfr[0], aO, 0, 0, 0);
        if (w >= 8) {
            aE = __builtin_amdgcn_mfma_f32_16x16x32_bf16(a01, bfr[1], aE, 0, 0, 0);
            aO = __builtin_amdgcn_mfma_f32_16x16x32_bf16(a11, bfr[1], aO, 0, 0, 0);
        }

        // lane owns layer l = 4w+quad, sample s16: full hidden vector
        const float t0 = th(aE[0]), t1 = th(aE[1]), t2 = th(aE[2]), t3 = th(aE[3]);
        const float t4 = th(aO[0]), t5 = th(aO[1]), t6 = th(aO[2]), t7 = th(aO[3]);

        const int l = 4 * w + quad;
        const float4 m0 = *(const float4*)(w2f + l * 16);        // broadcast reads
        const float4 m1 = *(const float4*)(w2f + l * 16 + 4);
        const float4 a0 = *(const float4*)(w2f + l * 16 + 8);
        const float4 a1 = *(const float4*)(w2f + l * 16 + 12);
        const float2 bb = *(const float2*)(b2f + l * 2);

        float mu = bb.x;
        mu = fmaf(m0.x, t0, mu); mu = fmaf(m0.y, t1, mu);
        mu = fmaf(m0.z, t2, mu); mu = fmaf(m0.w, t3, mu);
        mu = fmaf(m1.x, t4, mu); mu = fmaf(m1.y, t5, mu);
        mu = fmaf(m1.z, t6, mu); mu = fmaf(m1.w, t7, mu);
        float al = bb.y;
        al = fmaf(a0.x, t0, al); al = fmaf(a0.y, t1, al);
        al = fmaf(a0.z, t2, al); al = fmaf(a0.w, t3, al);
        al = fmaf(a1.x, t4, al); al = fmaf(a1.y, t5, al);
        al = fmaf(a1.z, t6, al); al = fmaf(a1.w, t7, al);

        // epilogue: z[d=l+1] in-place in LDS (l=63 pad lane handles d=0 instead)
        const bool pad = (l == 63);
        const float alB = pad ? ip1 : al;
        const float muB = pad ? ip0 : mu;
        const int d = pad ? 0 : (l + 1);
        float* pz = xzw + s16 * 64 + ((((d >> 2) ^ s16) & 15) << 2) + (d & 3);
        *pz = fmaf(*pz, __expf(alB), muB);
        lsum += alB;
    }

    // ---- coalesced LDS -> global z store ----
    #pragma unroll
    for (int g = 0; g < 4; ++g) {
        const int s_loc = 4 * g + quad;
        const int pc = (s16 ^ s_loc) & 15;
        const float4 v = *(const float4*)(xzw + s_loc * 64 + pc * 4);
        ((float4*)(out + (size_t)sbase * DIMS))[g * 64 + lane] = v;
    }

    // ---- log_det: sum the 4 quad-partials per sample ----
    {
        float v = lsum;
        int r1 = __builtin_amdgcn_ds_swizzle(__float_as_int(v), 0x401F);  // xor 16
        v += __int_as_float(r1);
        int r2 = __builtin_amdgcn_ds_bpermute((lane ^ 32) << 2, __float_as_int(v));
        v += __int_as_float(r2);
        if (quad == 0)
            out[(size_t)nB * DIMS + sbase + s16] = v;
    }
}

extern "C" void kernel_launch(void* const* d_in, const int* in_sizes, int n_in,
                              void* d_out, int out_size, void* d_ws, size_t ws_size,
                              hipStream_t stream) {
    const float* x  = (const float*)d_in[0];
    const float* ip = (const float*)d_in[1];
    const float* W1 = (const float*)d_in[2];
    const float* b1 = (const float*)d_in[3];
    const float* W2 = (const float*)d_in[4];
    const float* b2 = (const float*)d_in[5];
    float* out = (float*)d_out;
    (void)d_ws; (void)ws_size;              // workspace unused (poison is unconditional)

    const int nB = in_sizes[0] / DIMS;      // 131072

    (void)hipFuncSetAttribute((const void*)siaf_main,
                              hipFuncAttributeMaxDynamicSharedMemorySize, LDS_BYTES);

    siaf_main<<<nB / (WAVES * SPW), TPB, LDS_BYTES, stream>>>(
        x, ip, W1, b1, W2, b2, out, nB);
}

// Round 3
// 114.209 us; speedup vs baseline: 1.1314x; 1.1314x over previous
//
#include <hip/hip_runtime.h>

// SIAF forward. Round 10: revert to round-8 two-kernel structure (prep -> g_ws,
// known-good 112.7 us) + forced-ILP main loop.
// Round-9 lesson: fusing prep into main cost +17 us (scattered dependent global
// gathers x512 blocks). Prep stays a separate one-shot kernel.
// Round-9 counters for the compute path: MfmaUtil 4%, VALUBusy ~48%, VGPR=32 (!),
// occupancy 34% -> main (~39 us) is LATENCY-bound with no ILP: compiler
// register-minimized the window loop into a serial chain. This round forces ILP:
//   - double-buffered (w+1) prefetch of A-frags + b1 bias into registers
//   - GEMM2 broadcast LDS reads issued before the MFMAs of the same window
//   - mu/al FMA chains split into two 4-deep partials (was 8-deep serial)
//   - epilogue exp via exp2 (alpha bounded, no clamp fixups)
//   - x-stage global loads issued before the 56 KB weight copy
// Budget: 128 VGPR/wave at 4 waves/SIMD; pipelined regs ~100.

#define DIMS 64
#define TPB  1024
#define WAVES 16
#define SPW  16

typedef __attribute__((ext_vector_type(8))) short short8;
typedef __attribute__((ext_vector_type(4))) float f32x4;
typedef __attribute__((ext_vector_type(4))) unsigned int uint4v;
typedef unsigned short ushort_t;
typedef unsigned int uint_t;

#if __has_builtin(__builtin_amdgcn_exp2f)
#define YSCALE 2.8853900817779268f      /* 2*log2(e): exp(2y) = exp2(YSCALE*y) */
#define EXPY(x) __builtin_amdgcn_exp2f(x)
#define EXP2F(x) __builtin_amdgcn_exp2f(x)
#else
#define YSCALE 2.0f
#define EXPY(x) __expf(x)
#define EXP2F(x) exp2f(x)
#endif
#define LOG2E 1.4426950408889634f

// LDS/ws image layout (bytes):
//  A [0,16384):      w1 rows 0..255 (l<32), 64 B/row (k<32 only), 4-chunk XOR swizzle
//  B [16384,49152):  w1 rows 256..511, 128 B/row, 8-chunk XOR swizzle
//  C [49152,53248):  W2 fp32 [64 l][2 o][8 h]
//  D [53248,55296):  b1 fp32 [512] in physical (permuted) row order, YSCALE-scaled
//  E [55296,55808):  b2 fp32 [64][2]
#define A_OFF 0
#define B_OFF 16384
#define C_OFF 49152
#define D_OFF 53248
#define E_OFF 55296
#define WT_BYTES 55808
#define WT_CHUNKS (WT_BYTES / 16)
#define XZ_OFF WT_BYTES
#define LDS_BYTES (WT_BYTES + WAVES * SPW * DIMS * 4)   // 55808 + 65536 = 121344
#define PREP_N (24576 + 1664)

// Static device-side scratch for the prepped weight image (56 KB). d_ws is not
// used: the harness's 256 MiB workspace re-poison is unconditional either way.
__device__ __align__(16) unsigned char g_ws[WT_BYTES];

__device__ __forceinline__ uint_t pk2bf(float a, float b) {
#if __has_builtin(__builtin_amdgcn_cvt_pk_bf16_f32)
    typedef __attribute__((ext_vector_type(2))) __bf16 bf16x2;
    bf16x2 r = __builtin_amdgcn_cvt_pk_bf16_f32(a, b);
    return __builtin_bit_cast(uint_t, r);
#else
    uint_t ua = __float_as_uint(a); ua += 0x7FFFu + ((ua >> 16) & 1u);
    uint_t ub = __float_as_uint(b); ub += 0x7FFFu + ((ub >> 16) & 1u);
    return (ub & 0xFFFF0000u) | (ua >> 16);
#endif
}

__device__ __forceinline__ ushort_t f2bf(float f) {
    uint_t u = __float_as_uint(f);
    u += 0x7FFFu + ((u >> 16) & 1u);
    return (ushort_t)(u >> 16);
}

// logical row L for physical GEMM1 row p (window w=p>>5, tile parity e=(p>>4)&1,
// n=p&15): L = w*32 + (n>>2)*8 + e*4 + (n&3);  l = L>>3, h = L&7.
__device__ __forceinline__ int logrow(int p) {
    int n = p & 15;
    return (p >> 5) * 32 + (n >> 2) * 8 + ((p >> 4) & 1) * 4 + (n & 3);
}

__global__ void siaf_prep(const float* __restrict__ W1, const float* __restrict__ b1,
                          const float* __restrict__ W2, const float* __restrict__ b2) {
    ushort_t* __restrict__ ws_u = (ushort_t*)g_ws;
    int i = blockIdx.x * 256 + threadIdx.x;
    if (i < 8192) {                       // region A: p<256, 32 ushorts/row
        int p = i >> 5, e = i & 31;
        int cp = e >> 3, j = e & 7;
        int k = ((cp ^ (p & 3)) << 3) | j;          // de-swizzled logical k (<32)
        int L = logrow(p), l = L >> 3, h = L & 7;
        float v = (k <= l) ? W1[(l * 8 + h) * 63 + k] * YSCALE : 0.0f;
        ws_u[i] = f2bf(v);
    } else if (i < 24576) {               // region B: p in [256,512), 64 ushorts/row
        int v_ = i - 8192;
        int p = 256 + (v_ >> 6), e = v_ & 63;
        int cp = e >> 3, j = e & 7;
        int k = ((cp ^ (p & 7)) << 3) | j;
        int L = logrow(p), l = L >> 3, h = L & 7;
        float v = (l < 63 && k <= l) ? W1[(l * 8 + h) * 63 + k] * YSCALE : 0.0f;
        ws_u[i] = f2bf(v);
    } else if (i < PREP_N) {              // fp32 regions C/D/E
        int f = i - 24576;
        float* fws = (float*)(ws_u + 24576);
        float v = 0.0f;
        if (f < 1024) {                   // C: W2 [l][o][h]
            int l = f >> 4, o = (f >> 3) & 1, h = f & 7;
            if (l < 63) v = W2[(l * 2 + o) * 8 + h];
        } else if (f < 1536) {            // D: b1 in physical row order
            int p = f - 1024;
            int L = logrow(p), l = L >> 3, h = L & 7;
            if (l < 63) v = b1[l * 8 + h] * YSCALE;
        } else {                          // E: b2 [l][o]
            int j = f - 1536, l = j >> 1, o = j & 1;
            if (l < 63) v = b2[l * 2 + o];
        }
        fws[f] = v;
    }
}

__device__ __forceinline__ float th(float t) {
    // t = YSCALE*y ; tanh(y) = 1 - 2/(exp2(t)+1)
    float e = EXPY(t);
    float r = __builtin_amdgcn_rcpf(e + 1.0f);
    return fmaf(-2.0f, r, 1.0f);
}

__global__ __launch_bounds__(TPB, 4) void siaf_main(
        const float* __restrict__ x, const float* __restrict__ ip,
        float* __restrict__ out, int nB) {
    extern __shared__ unsigned char lds[];

    const int tid  = threadIdx.x;
    const int wv   = tid >> 6, lane = tid & 63;
    const int s16  = lane & 15, quad = lane >> 4;
    const int sbase = blockIdx.x * (WAVES * SPW) + wv * SPW;
    float* xzw = (float*)(lds + XZ_OFF) + wv * (SPW * DIMS);

    // ---- stage x FIRST (own-wave LDS region, no barrier dependency) so the
    // global loads are in flight while the weight image is copied below.
    #pragma unroll
    for (int g = 0; g < 4; ++g) {
        const float4 v = ((const float4*)(x + (size_t)sbase * DIMS))[g * 64 + lane];
        const int s_loc = 4 * g + quad;
        const int pc = (s16 ^ s_loc) & 15;
        *(float4*)(xzw + s_loc * 64 + pc * 4) = v;
    }
    const float ip0 = ip[0], ip1 = ip[1];

    // ---- stage the 56 KB weight image (already in final layout) ----
    {
        const uint4* __restrict__ wsv = (const uint4*)g_ws;
        uint4* dst = (uint4*)lds;
        for (int c = tid; c < WT_CHUNKS; c += TPB) dst[c] = wsv[c];
    }

    // ---- B-frag: B[k=quad*8+j][n=s16] from own-wave LDS region, bf16 ----
    short8 bfr[2];
    #pragma unroll
    for (int kh = 0; kh < 2; ++kh) {
        const int c0 = kh * 8 + quad * 2;
        float4 va = *(const float4*)(xzw + s16 * 64 + ((c0 ^ s16) & 15) * 4);
        float4 vb = *(const float4*)(xzw + s16 * 64 + (((c0 + 1) ^ s16) & 15) * 4);
        uint4v u = {pk2bf(va.x, va.y), pk2bf(va.z, va.w),
                    pk2bf(vb.x, vb.y), pk2bf(vb.z, vb.w)};
        bfr[kh] = __builtin_bit_cast(short8, u);
    }

    __syncthreads();   // weight image ready for all waves

    const ushort_t* wA  = (const ushort_t*)(lds + A_OFF);
    const ushort_t* wB  = (const ushort_t*)(lds + B_OFF);
    const float*    w2f = (const float*)(lds + C_OFF);
    const float*    b1f = (const float*)(lds + D_OFF);
    const float*    b2f = (const float*)(lds + E_OFF);

    // A-frag loader for window w (compile-time w under full unroll)
    auto ldfr = [&](int w, short8& a00, short8& a10, short8& a01, short8& a11) {
        if (w < 8) {
            const ushort_t* base = wA + (w * 32 + s16) * 32;        // 64 B rows
            const int pc = quad ^ (s16 & 3);
            a00 = *(const short8*)(base + pc * 8);
            a10 = *(const short8*)(base + 512 + pc * 8);            // +16 rows
        } else {
            const ushort_t* base = wB + ((w - 8) * 32 + s16) * 64;  // 128 B rows
            const int pc = quad ^ (s16 & 7);
            a00 = *(const short8*)(base + pc * 8);
            a10 = *(const short8*)(base + 1024 + pc * 8);
            a01 = *(const short8*)(base + (pc ^ 4) * 8);
            a11 = *(const short8*)(base + 1024 + (pc ^ 4) * 8);
        }
    };
    auto ldbi = [&](int w, float4& bi0, float4& bi1) {
        bi0 = *(const float4*)(b1f + w * 32 + quad * 4);            // broadcast
        bi1 = *(const float4*)(b1f + w * 32 + 16 + quad * 4);       // broadcast
    };

    // Pipelined registers: double-buffered MFMA inputs (A-frags + b1 bias)
    short8 A00[2], A10[2], A01[2] = {}, A11[2] = {};
    float4 BI0[2], BI1[2];
    ldfr(0, A00[0], A10[0], A01[0], A11[0]);
    ldbi(0, BI0[0], BI1[0]);

    float lsum = 0.0f;
    #pragma unroll
    for (int w = 0; w < 16; ++w) {
        const int cur = w & 1, nxt = cur ^ 1;

        // GEMM2 broadcast reads for THIS window, issued before the MFMAs so
        // their LDS latency hides under MFMA + tanh.
        const int l = 4 * w + quad;
        const float4 m0 = *(const float4*)(w2f + l * 16);
        const float4 m1 = *(const float4*)(w2f + l * 16 + 4);
        const float4 a0 = *(const float4*)(w2f + l * 16 + 8);
        const float4 a1 = *(const float4*)(w2f + l * 16 + 12);
        const float2 bb = *(const float2*)(b2f + l * 2);

        // prefetch NEXT window's MFMA inputs
        if (w < 15) {
            ldfr(w + 1, A00[nxt], A10[nxt], A01[nxt], A11[nxt]);
            ldbi(w + 1, BI0[nxt], BI1[nxt]);
        }

        f32x4 aE = {BI0[cur].x, BI0[cur].y, BI0[cur].z, BI0[cur].w};
        f32x4 aO = {BI1[cur].x, BI1[cur].y, BI1[cur].z, BI1[cur].w};
        aE = __builtin_amdgcn_mfma_f32_16x16x32_bf16(A00[cur], bfr[0], aE, 0, 0, 0);
        aO = __builtin_amdgcn_mfma_f32_16x16x32_bf16(A10[cur], bfr[0], aO, 0, 0, 0);
        if (w >= 8) {
            aE = __builtin_amdgcn_mfma_f32_16x16x32_bf16(A01[cur], bfr[1], aE, 0, 0, 0);
            aO = __builtin_amdgcn_mfma_f32_16x16x32_bf16(A11[cur], bfr[1], aO, 0, 0, 0);
        }

        // lane owns layer l = 4w+quad, sample s16: full hidden vector
        const float t0 = th(aE[0]), t1 = th(aE[1]), t2 = th(aE[2]), t3 = th(aE[3]);
        const float t4 = th(aO[0]), t5 = th(aO[1]), t6 = th(aO[2]), t7 = th(aO[3]);

        // GEMM2: two 4-deep partials per output (was one 8-deep serial chain)
        float mu0 = bb.x, mu1 = m1.x * t4;
        mu0 = fmaf(m0.x, t0, mu0); mu1 = fmaf(m1.y, t5, mu1);
        mu0 = fmaf(m0.y, t1, mu0); mu1 = fmaf(m1.z, t6, mu1);
        mu0 = fmaf(m0.z, t2, mu0); mu1 = fmaf(m1.w, t7, mu1);
        mu0 = fmaf(m0.w, t3, mu0);
        const float mu = mu0 + mu1;
        float al0 = bb.y, al1 = a1.x * t4;
        al0 = fmaf(a0.x, t0, al0); al1 = fmaf(a1.y, t5, al1);
        al0 = fmaf(a0.y, t1, al0); al1 = fmaf(a1.z, t6, al1);
        al0 = fmaf(a0.z, t2, al0); al1 = fmaf(a1.w, t7, al1);
        al0 = fmaf(a0.w, t3, al0);
        const float al = al0 + al1;

        // epilogue: z[d=l+1] in-place in LDS (l=63 pad lane handles d=0 instead)
        const bool pad = (l == 63);
        const float alB = pad ? ip1 : al;
        const float muB = pad ? ip0 : mu;
        const int d = pad ? 0 : (l + 1);
        float* pz = xzw + s16 * 64 + ((((d >> 2) ^ s16) & 15) << 2) + (d & 3);
        // |alpha| <= |b2| + sum|W2| < 3.2 -> exp2 input < 4.7, no clamp needed
        *pz = fmaf(*pz, EXP2F(alB * LOG2E), muB);
        lsum += alB;
    }

    // ---- coalesced LDS -> global z store ----
    #pragma unroll
    for (int g = 0; g < 4; ++g) {
        const int s_loc = 4 * g + quad;
        const int pc = (s16 ^ s_loc) & 15;
        const float4 v = *(const float4*)(xzw + s_loc * 64 + pc * 4);
        ((float4*)(out + (size_t)sbase * DIMS))[g * 64 + lane] = v;
    }

    // ---- log_det: sum the 4 quad-partials per sample ----
    {
        float v = lsum;
        int r1 = __builtin_amdgcn_ds_swizzle(__float_as_int(v), 0x401F);  // xor 16
        v += __int_as_float(r1);
        int r2 = __builtin_amdgcn_ds_bpermute((lane ^ 32) << 2, __float_as_int(v));
        v += __int_as_float(r2);
        if (quad == 0)
            out[(size_t)nB * DIMS + sbase + s16] = v;
    }
}

extern "C" void kernel_launch(void* const* d_in, const int* in_sizes, int n_in,
                              void* d_out, int out_size, void* d_ws, size_t ws_size,
                              hipStream_t stream) {
    const float* x  = (const float*)d_in[0];
    const float* ip = (const float*)d_in[1];
    const float* W1 = (const float*)d_in[2];
    const float* b1 = (const float*)d_in[3];
    const float* W2 = (const float*)d_in[4];
    const float* b2 = (const float*)d_in[5];
    float* out = (float*)d_out;
    (void)d_ws; (void)ws_size;              // workspace unused (poison is unconditional)

    const int nB = in_sizes[0] / DIMS;      // 131072

    (void)hipFuncSetAttribute((const void*)siaf_main,
                              hipFuncAttributeMaxDynamicSharedMemorySize, LDS_BYTES);

    siaf_prep<<<(PREP_N + 255) / 256, 256, 0, stream>>>(W1, b1, W2, b2);
    siaf_main<<<nB / (WAVES * SPW), TPB, LDS_BYTES, stream>>>(x, ip, out, nB);
}

// Round 4
// 114.034 us; speedup vs baseline: 1.1331x; 1.0015x over previous
//
#include <hip/hip_runtime.h>

// SIAF forward. Round 11: occupancy attack. Rounds 9-10 showed main is
// latency-bound at 4 waves/SIMD (VALUBusy ~48%, VGPR 32, in-loop ILP neutral).
// The 56 KB LDS weight image was capping us at 1 block/CU; but the per-window
// A-frag reads are the SAME 48 KB for every wave on the chip -- an ideal
// L1/L2 broadcast set, no better served from LDS (L1 ~100-200cyc vs LDS ~120).
// This round:
//   - W1 A-frags stream directly from a LINEAR global image (no swizzle needed;
//     each wave-load is a coalesced permutation of a contiguous 1 KB block).
//     Regions: A (w<8, k<32) / B-lo (w>=8, k<32) / B-hi (w>=8, k>=32), 64 B rows.
//   - LDS keeps only C/D/E (6.7 KB broadcast weights) + 32 KB x/z transpose.
//   - 512-thread blocks (8 waves x 16 samples), 39.4 KB LDS -> 4 blocks/CU,
//     8 waves/SIMD (launch_bounds(512,8) caps VGPR at 64), 4-deep block overlap.
//   - round-10 double-buffered A-frag prefetch retained (now overlapping real
//     VMEM latency); bias/GEMM2 weights read from LDS at use (broadcast, cheap).
// Watch-for: VGPR spills under the 64 cap (fallback: hybrid w<8-in-LDS).

#define DIMS 64
#define TPB  512
#define WAVES 8
#define SPW  16

typedef __attribute__((ext_vector_type(8))) short short8;
typedef __attribute__((ext_vector_type(4))) float f32x4;
typedef __attribute__((ext_vector_type(4))) unsigned int uint4v;
typedef unsigned short ushort_t;
typedef unsigned int uint_t;

#if __has_builtin(__builtin_amdgcn_exp2f)
#define YSCALE 2.8853900817779268f      /* 2*log2(e): exp(2y) = exp2(YSCALE*y) */
#define EXPY(x) __builtin_amdgcn_exp2f(x)
#define EXP2F(x) __builtin_amdgcn_exp2f(x)
#else
#define YSCALE 2.0f
#define EXPY(x) __expf(x)
#define EXP2F(x) exp2f(x)
#endif
#define LOG2E 1.4426950408889634f

// g_ws global image layout (bytes) -- LINEAR, built for coalesced global reads:
//  A   [0,16384):      w1 rows p<256 (w<8), 64 B/row, k=0..31
//  Blo [16384,32768):  w1 rows p in [256,512), 64 B/row, k=0..31
//  Bhi [32768,49152):  w1 rows p in [256,512), 64 B/row, k=32..63
//  C   [49152,53248):  W2 fp32 [64 l][2 o][8 h]
//  D   [53248,55296):  b1 fp32 [512] in physical (permuted) row order, YSCALE-scaled
//  E   [55296,55808):  b2 fp32 [64][2]
#define A_OFF 0
#define BLO_OFF 16384
#define BHI_OFF 32768
#define C_OFF 49152
#define WT_BYTES 55808
#define CDE_BYTES 6656
#define PREP_N (24576 + 1664)

// LDS layout: [0,4096) W2 | [4096,6144) b1 | [6144,6656) b2 | [6656,+32768) xz
#define XZ_OFF CDE_BYTES
#define LDS_BYTES (CDE_BYTES + WAVES * SPW * DIMS * 4)   // 6656 + 32768 = 39424

__device__ __align__(16) unsigned char g_ws[WT_BYTES];

__device__ __forceinline__ uint_t pk2bf(float a, float b) {
#if __has_builtin(__builtin_amdgcn_cvt_pk_bf16_f32)
    typedef __attribute__((ext_vector_type(2))) __bf16 bf16x2;
    bf16x2 r = __builtin_amdgcn_cvt_pk_bf16_f32(a, b);
    return __builtin_bit_cast(uint_t, r);
#else
    uint_t ua = __float_as_uint(a); ua += 0x7FFFu + ((ua >> 16) & 1u);
    uint_t ub = __float_as_uint(b); ub += 0x7FFFu + ((ub >> 16) & 1u);
    return (ub & 0xFFFF0000u) | (ua >> 16);
#endif
}

__device__ __forceinline__ ushort_t f2bf(float f) {
    uint_t u = __float_as_uint(f);
    u += 0x7FFFu + ((u >> 16) & 1u);
    return (ushort_t)(u >> 16);
}

// logical row L for physical GEMM1 row p (window w=p>>5, tile parity e=(p>>4)&1,
// n=p&15): L = w*32 + (n>>2)*8 + e*4 + (n&3);  l = L>>3, h = L&7.
__device__ __forceinline__ int logrow(int p) {
    int n = p & 15;
    return (p >> 5) * 32 + (n >> 2) * 8 + ((p >> 4) & 1) * 4 + (n & 3);
}

__global__ void siaf_prep(const float* __restrict__ W1, const float* __restrict__ b1,
                          const float* __restrict__ W2, const float* __restrict__ b2) {
    ushort_t* __restrict__ ws_u = (ushort_t*)g_ws;
    int i = blockIdx.x * 256 + threadIdx.x;
    if (i < 8192) {                       // region A: p<256, k = e (linear!)
        int p = i >> 5, k = i & 31;
        int L = logrow(p), l = L >> 3, h = L & 7;
        float v = (k <= l) ? W1[(l * 8 + h) * 63 + k] * YSCALE : 0.0f;
        ws_u[i] = f2bf(v);
    } else if (i < 16384) {               // region B-lo: p in [256,512), k<32
        int r = i - 8192;
        int p = 256 + (r >> 5), k = r & 31;
        int L = logrow(p), l = L >> 3, h = L & 7;
        float v = (l < 63 && k <= l) ? W1[(l * 8 + h) * 63 + k] * YSCALE : 0.0f;
        ws_u[i] = f2bf(v);
    } else if (i < 24576) {               // region B-hi: p in [256,512), k>=32
        int r = i - 16384;
        int p = 256 + (r >> 5), k = 32 + (r & 31);
        int L = logrow(p), l = L >> 3, h = L & 7;
        float v = (l < 63 && k <= l) ? W1[(l * 8 + h) * 63 + k] * YSCALE : 0.0f;
        ws_u[i] = f2bf(v);
    } else if (i < PREP_N) {              // fp32 regions C/D/E
        int f = i - 24576;
        float* fws = (float*)(ws_u + 24576);
        float v = 0.0f;
        if (f < 1024) {                   // C: W2 [l][o][h]
            int l = f >> 4, o = (f >> 3) & 1, h = f & 7;
            if (l < 63) v = W2[(l * 2 + o) * 8 + h];
        } else if (f < 1536) {            // D: b1 in physical row order
            int p = f - 1024;
            int L = logrow(p), l = L >> 3, h = L & 7;
            if (l < 63) v = b1[l * 8 + h] * YSCALE;
        } else {                          // E: b2 [l][o]
            int j = f - 1536, l = j >> 1, o = j & 1;
            if (l < 63) v = b2[l * 2 + o];
        }
        fws[f] = v;
    }
}

__device__ __forceinline__ float th(float t) {
    // t = YSCALE*y ; tanh(y) = 1 - 2/(exp2(t)+1)
    float e = EXPY(t);
    float r = __builtin_amdgcn_rcpf(e + 1.0f);
    return fmaf(-2.0f, r, 1.0f);
}

__global__ __launch_bounds__(TPB, 8) void siaf_main(
        const float* __restrict__ x, const float* __restrict__ ip,
        float* __restrict__ out, int nB) {
    extern __shared__ unsigned char lds[];

    const int tid  = threadIdx.x;
    const int wv   = tid >> 6, lane = tid & 63;
    const int s16  = lane & 15, quad = lane >> 4;
    const int sbase = blockIdx.x * (WAVES * SPW) + wv * SPW;
    float* xzw = (float*)(lds + XZ_OFF) + wv * (SPW * DIMS);

    // ---- stage x (own-wave LDS region): coalesced 1KB/instr, 16B-chunk XOR
    // swizzle (key = row). Issued first so global latency overlaps CDE stage.
    #pragma unroll
    for (int g = 0; g < 4; ++g) {
        const float4 v = ((const float4*)(x + (size_t)sbase * DIMS))[g * 64 + lane];
        const int s_loc = 4 * g + quad;
        const int pc = (s16 ^ s_loc) & 15;
        *(float4*)(xzw + s_loc * 64 + pc * 4) = v;
    }
    const float ip0 = ip[0], ip1 = ip[1];

    // ---- stage C/D/E (6656 B) into LDS ----
    if (tid < CDE_BYTES / 16) {
        ((uint4*)lds)[tid] = ((const uint4*)(g_ws + C_OFF))[tid];
    }

    // ---- B-frag: B[k=quad*8+j][n=s16] from own-wave LDS region, bf16 ----
    short8 bfr[2];
    #pragma unroll
    for (int kh = 0; kh < 2; ++kh) {
        const int c0 = kh * 8 + quad * 2;
        float4 va = *(const float4*)(xzw + s16 * 64 + ((c0 ^ s16) & 15) * 4);
        float4 vb = *(const float4*)(xzw + s16 * 64 + (((c0 + 1) ^ s16) & 15) * 4);
        uint4v u = {pk2bf(va.x, va.y), pk2bf(va.z, va.w),
                    pk2bf(vb.x, vb.y), pk2bf(vb.z, vb.w)};
        bfr[kh] = __builtin_bit_cast(short8, u);
    }

    __syncthreads();   // C/D/E image ready for all waves

    const float* w2f = (const float*)(lds);
    const float* b1f = (const float*)(lds + 4096);
    const float* b2f = (const float*)(lds + 6144);

    // W1 A-frags stream from the linear global image. A wave's 64 lanes read a
    // permutation of one contiguous 1 KB block per load -> fully coalesced,
    // L1/L2-resident (48 KB shared by every wave on the chip).
    const ushort_t* gA   = (const ushort_t*)g_ws;            // + A_OFF
    const ushort_t* gBlo = (const ushort_t*)(g_ws + BLO_OFF);
    const ushort_t* gBhi = (const ushort_t*)(g_ws + BHI_OFF);
    const int fo = s16 * 32 + quad * 8;    // lane offset within a window plane

    auto ldA = [&](int w, short8& a00, short8& a10, short8& a01, short8& a11) {
        if (w < 8) {
            const ushort_t* b = gA + w * 1024 + fo;
            a00 = *(const short8*)(b);
            a10 = *(const short8*)(b + 512);         // rows +16
        } else {
            const int off = (w - 8) * 1024 + fo;
            a00 = *(const short8*)(gBlo + off);
            a10 = *(const short8*)(gBlo + off + 512);
            a01 = *(const short8*)(gBhi + off);
            a11 = *(const short8*)(gBhi + off + 512);
        }
    };

    // double-buffered A-frag prefetch (VMEM latency overlap)
    short8 A00[2], A10[2], A01[2] = {}, A11[2] = {};
    ldA(0, A00[0], A10[0], A01[0], A11[0]);

    float lsum = 0.0f;
    #pragma unroll
    for (int w = 0; w < 16; ++w) {
        const int cur = w & 1, nxt = cur ^ 1;

        // prefetch NEXT window's A-frags (global, long latency) first
        if (w < 15) ldA(w + 1, A00[nxt], A10[nxt], A01[nxt], A11[nxt]);

        // bias (broadcast LDS reads) -> accumulator init
        const float4 bi0 = *(const float4*)(b1f + w * 32 + quad * 4);
        const float4 bi1 = *(const float4*)(b1f + w * 32 + 16 + quad * 4);

        f32x4 aE = {bi0.x, bi0.y, bi0.z, bi0.w};
        f32x4 aO = {bi1.x, bi1.y, bi1.z, bi1.w};
        aE = __builtin_amdgcn_mfma_f32_16x16x32_bf16(A00[cur], bfr[0], aE, 0, 0, 0);
        aO = __builtin_amdgcn_mfma_f32_16x16x32_bf16(A10[cur], bfr[0], aO, 0, 0, 0);
        if (w >= 8) {
            aE = __builtin_amdgcn_mfma_f32_16x16x32_bf16(A01[cur], bfr[1], aE, 0, 0, 0);
            aO = __builtin_amdgcn_mfma_f32_16x16x32_bf16(A11[cur], bfr[1], aO, 0, 0, 0);
        }

        // lane owns layer l = 4w+quad, sample s16: full hidden vector
        const float t0 = th(aE[0]), t1 = th(aE[1]), t2 = th(aE[2]), t3 = th(aE[3]);
        const float t4 = th(aO[0]), t5 = th(aO[1]), t6 = th(aO[2]), t7 = th(aO[3]);

        // GEMM2: broadcast LDS reads, two 4-deep FMA partials per output
        const int l = 4 * w + quad;
        const float4 m0 = *(const float4*)(w2f + l * 16);
        const float4 m1 = *(const float4*)(w2f + l * 16 + 4);
        const float4 a0 = *(const float4*)(w2f + l * 16 + 8);
        const float4 a1 = *(const float4*)(w2f + l * 16 + 12);
        const float2 bb = *(const float2*)(b2f + l * 2);

        float mu0 = bb.x, mu1 = m1.x * t4;
        mu0 = fmaf(m0.x, t0, mu0); mu1 = fmaf(m1.y, t5, mu1);
        mu0 = fmaf(m0.y, t1, mu0); mu1 = fmaf(m1.z, t6, mu1);
        mu0 = fmaf(m0.z, t2, mu0); mu1 = fmaf(m1.w, t7, mu1);
        mu0 = fmaf(m0.w, t3, mu0);
        const float mu = mu0 + mu1;
        float al0 = bb.y, al1 = a1.x * t4;
        al0 = fmaf(a0.x, t0, al0); al1 = fmaf(a1.y, t5, al1);
        al0 = fmaf(a0.y, t1, al0); al1 = fmaf(a1.z, t6, al1);
        al0 = fmaf(a0.z, t2, al0); al1 = fmaf(a1.w, t7, al1);
        al0 = fmaf(a0.w, t3, al0);
        const float al = al0 + al1;

        // epilogue: z[d=l+1] in-place in LDS (l=63 pad lane handles d=0 instead)
        const bool pad = (l == 63);
        const float alB = pad ? ip1 : al;
        const float muB = pad ? ip0 : mu;
        const int d = pad ? 0 : (l + 1);
        float* pz = xzw + s16 * 64 + ((((d >> 2) ^ s16) & 15) << 2) + (d & 3);
        // |alpha| <= |b2| + sum|W2| < 3.2 -> exp2 input < 4.7, no clamp needed
        *pz = fmaf(*pz, EXP2F(alB * LOG2E), muB);
        lsum += alB;
    }

    // ---- coalesced LDS -> global z store ----
    #pragma unroll
    for (int g = 0; g < 4; ++g) {
        const int s_loc = 4 * g + quad;
        const int pc = (s16 ^ s_loc) & 15;
        const float4 v = *(const float4*)(xzw + s_loc * 64 + pc * 4);
        ((float4*)(out + (size_t)sbase * DIMS))[g * 64 + lane] = v;
    }

    // ---- log_det: sum the 4 quad-partials per sample ----
    {
        float v = lsum;
        int r1 = __builtin_amdgcn_ds_swizzle(__float_as_int(v), 0x401F);  // xor 16
        v += __int_as_float(r1);
        int r2 = __builtin_amdgcn_ds_bpermute((lane ^ 32) << 2, __float_as_int(v));
        v += __int_as_float(r2);
        if (quad == 0)
            out[(size_t)nB * DIMS + sbase + s16] = v;
    }
}

extern "C" void kernel_launch(void* const* d_in, const int* in_sizes, int n_in,
                              void* d_out, int out_size, void* d_ws, size_t ws_size,
                              hipStream_t stream) {
    const float* x  = (const float*)d_in[0];
    const float* ip = (const float*)d_in[1];
    const float* W1 = (const float*)d_in[2];
    const float* b1 = (const float*)d_in[3];
    const float* W2 = (const float*)d_in[4];
    const float* b2 = (const float*)d_in[5];
    float* out = (float*)d_out;
    (void)d_ws; (void)ws_size;              // workspace unused (poison is unconditional)

    const int nB = in_sizes[0] / DIMS;      // 131072

    (void)hipFuncSetAttribute((const void*)siaf_main,
                              hipFuncAttributeMaxDynamicSharedMemorySize, LDS_BYTES);

    siaf_prep<<<(PREP_N + 255) / 256, 256, 0, stream>>>(W1, b1, W2, b2);
    siaf_main<<<nB / (WAVES * SPW), TPB, LDS_BYTES, stream>>>(x, ip, out, nB);
}

// Round 5
// 113.638 us; speedup vs baseline: 1.1371x; 1.0035x over previous
//
#include <hip/hip_runtime.h>
#include <hip/hip_cooperative_groups.h>

// SIAF forward. Round 12: instruction diet + single cooperative launch.
// Rounds 9-11 established: main is ISSUE-bound (per-SIMD total work invariant
// across 1->4 blocks/CU; VALUBusy ~48%, MfmaUtil 4%), so occupancy/pipelining
// moves nothing. Levers: delete instructions, delete dispatches.
//  Diet: tanh(y)=1-2r, r=1/(exp2(t)+1); GEMM2 is linear in tanh -> fold the
//  affine part into prep: W2' = -2*W2 (alpha row also *log2e), b2' = b2+rowsum
//  (alpha row *log2e). Epilogue exp2 reads alpha directly in log2 domain;
//  log_det multiplied by ln2 once after reduction. Pad-lane selects hoisted to
//  the compile-time w==15 iteration. ~-190 VALU/thread (~15% of VALU issue).
//  Launch: one cooperative kernel = distributed prep (1 elem/thread, 52 blocks
//  participate) -> threadfence + grid.sync -> main body. Occupancy-query
//  guarded with a two-kernel fallback (both compiled).
// Carried: linear global W1 image (round 11), 512-thr blocks, 39.4 KB LDS,
// 4 blocks/CU, launch_bounds(512,8), double-buffered A-frag prefetch.

namespace cg = cooperative_groups;

#define DIMS 64
#define TPB  512
#define WAVES 8
#define SPW  16
#define GRID 1024     /* 131072 / (WAVES*SPW) */

typedef __attribute__((ext_vector_type(8))) short short8;
typedef __attribute__((ext_vector_type(4))) float f32x4;
typedef __attribute__((ext_vector_type(4))) unsigned int uint4v;
typedef unsigned short ushort_t;
typedef unsigned int uint_t;

#if __has_builtin(__builtin_amdgcn_exp2f)
#define YSCALE 2.8853900817779268f      /* 2*log2(e): exp(2y) = exp2(YSCALE*y) */
#define EXP2F(x) __builtin_amdgcn_exp2f(x)
#else
#define YSCALE 2.8853900817779268f
#define EXP2F(x) exp2f(x)
#endif
#define LOG2E 1.4426950408889634f
#define LN2   0.6931471805599453f

// g_ws global image layout (bytes) -- LINEAR, coalesced global reads:
//  A   [0,16384):      w1 rows p<256 (w<8), 64 B/row, k=0..31
//  Blo [16384,32768):  w1 rows p in [256,512), 64 B/row, k=0..31
//  Bhi [32768,49152):  w1 rows p in [256,512), 64 B/row, k=32..63
//  C'  [49152,53248):  -2*W2 fp32 [64 l][2 o][8 h], o=1 row additionally *LOG2E
//  D   [53248,55296):  b1 fp32 [512] physical row order, *YSCALE
//  E'  [55296,55808):  (b2+rowsum W2) fp32 [64][2], o=1 *LOG2E
#define A_OFF 0
#define BLO_OFF 16384
#define BHI_OFF 32768
#define C_OFF 49152
#define WT_BYTES 55808
#define CDE_BYTES 6656
#define PREP_N (24576 + 1664)

// LDS: [0,4096) W2' | [4096,6144) b1 | [6144,6656) b2' | [6656,+32768) xz
#define XZ_OFF CDE_BYTES
#define LDS_BYTES (CDE_BYTES + WAVES * SPW * DIMS * 4)   // 6656 + 32768 = 39424

__device__ __align__(16) unsigned char g_ws[WT_BYTES];

__device__ __forceinline__ uint_t pk2bf(float a, float b) {
#if __has_builtin(__builtin_amdgcn_cvt_pk_bf16_f32)
    typedef __attribute__((ext_vector_type(2))) __bf16 bf16x2;
    bf16x2 r = __builtin_amdgcn_cvt_pk_bf16_f32(a, b);
    return __builtin_bit_cast(uint_t, r);
#else
    uint_t ua = __float_as_uint(a); ua += 0x7FFFu + ((ua >> 16) & 1u);
    uint_t ub = __float_as_uint(b); ub += 0x7FFFu + ((ub >> 16) & 1u);
    return (ub & 0xFFFF0000u) | (ua >> 16);
#endif
}

__device__ __forceinline__ ushort_t f2bf(float f) {
    uint_t u = __float_as_uint(f);
    u += 0x7FFFu + ((u >> 16) & 1u);
    return (ushort_t)(u >> 16);
}

// logical row L for physical GEMM1 row p (window w=p>>5, tile parity e=(p>>4)&1,
// n=p&15): L = w*32 + (n>>2)*8 + e*4 + (n&3);  l = L>>3, h = L&7.
__device__ __forceinline__ int logrow(int p) {
    int n = p & 15;
    return (p >> 5) * 32 + (n >> 2) * 8 + ((p >> 4) & 1) * 4 + (n & 3);
}

__device__ __forceinline__ void prep_element(int i,
        const float* __restrict__ W1, const float* __restrict__ b1,
        const float* __restrict__ W2, const float* __restrict__ b2) {
    ushort_t* __restrict__ ws_u = (ushort_t*)g_ws;
    if (i < 8192) {                       // region A: p<256, linear k
        int p = i >> 5, k = i & 31;
        int L = logrow(p), l = L >> 3, h = L & 7;
        float v = (k <= l) ? W1[(l * 8 + h) * 63 + k] * YSCALE : 0.0f;
        ws_u[i] = f2bf(v);
    } else if (i < 16384) {               // region B-lo: p in [256,512), k<32
        int r = i - 8192;
        int p = 256 + (r >> 5), k = r & 31;
        int L = logrow(p), l = L >> 3, h = L & 7;
        float v = (l < 63 && k <= l) ? W1[(l * 8 + h) * 63 + k] * YSCALE : 0.0f;
        ws_u[i] = f2bf(v);
    } else if (i < 24576) {               // region B-hi: p in [256,512), k>=32
        int r = i - 16384;
        int p = 256 + (r >> 5), k = 32 + (r & 31);
        int L = logrow(p), l = L >> 3, h = L & 7;
        float v = (l < 63 && k <= l) ? W1[(l * 8 + h) * 63 + k] * YSCALE : 0.0f;
        ws_u[i] = f2bf(v);
    } else if (i < PREP_N) {              // fp32 regions C'/D/E'
        int f = i - 24576;
        float* fws = (float*)(g_ws + C_OFF);
        float v = 0.0f;
        if (f < 1024) {                   // C': -2*W2 (alpha row *LOG2E)
            int l = f >> 4, o = (f >> 3) & 1, h = f & 7;
            if (l < 63) {
                v = -2.0f * W2[(l * 2 + o) * 8 + h];
                if (o) v *= LOG2E;
            }
        } else if (f < 1536) {            // D: b1 in physical row order
            int p = f - 1024;
            int L = logrow(p), l = L >> 3, h = L & 7;
            if (l < 63) v = b1[l * 8 + h] * YSCALE;
        } else {                          // E': b2 + rowsum(W2) (alpha *LOG2E)
            int j = f - 1536, l = j >> 1, o = j & 1;
            if (l < 63) {
                float s = b2[l * 2 + o];
                #pragma unroll
                for (int h = 0; h < 8; ++h) s += W2[(l * 2 + o) * 8 + h];
                v = o ? s * LOG2E : s;
            }
        }
        fws[f] = v;
    }
}

__global__ void siaf_prep(const float* __restrict__ W1, const float* __restrict__ b1,
                          const float* __restrict__ W2, const float* __restrict__ b2) {
    prep_element(blockIdx.x * 256 + threadIdx.x, W1, b1, W2, b2);
}

// r = 1/(exp2(t)+1); tanh(y) = 1 - 2r is folded into W2'/b2'.
__device__ __forceinline__ float sg(float t) {
    float e = EXP2F(t);
    return __builtin_amdgcn_rcpf(e + 1.0f);
}

__device__ __forceinline__ void x_stage(float* xzw, const float* __restrict__ x,
                                        int sbase, int s16, int quad, int lane) {
    #pragma unroll
    for (int g = 0; g < 4; ++g) {
        const float4 v = ((const float4*)(x + (size_t)sbase * DIMS))[g * 64 + lane];
        const int s_loc = 4 * g + quad;
        const int pc = (s16 ^ s_loc) & 15;
        *(float4*)(xzw + s_loc * 64 + pc * 4) = v;
    }
}

__device__ __forceinline__ void siaf_body(
        unsigned char* lds, const float* __restrict__ x,
        const float* __restrict__ ip, float* __restrict__ out, int nB,
        bool stage_x) {
    const int tid  = threadIdx.x;
    const int wv   = tid >> 6, lane = tid & 63;
    const int s16  = lane & 15, quad = lane >> 4;
    const int sbase = blockIdx.x * (WAVES * SPW) + wv * SPW;
    float* xzw = (float*)(lds + XZ_OFF) + wv * (SPW * DIMS);

    if (stage_x) x_stage(xzw, x, sbase, s16, quad, lane);
    const float ip0 = ip[0];
    const float ip1l2 = ip[1] * LOG2E;

    // ---- stage C'/D/E' (6656 B) into LDS ----
    if (tid < CDE_BYTES / 16) {
        ((uint4*)lds)[tid] = ((const uint4*)(g_ws + C_OFF))[tid];
    }

    // ---- B-frag: B[k=quad*8+j][n=s16] from own-wave LDS region, bf16 ----
    short8 bfr[2];
    #pragma unroll
    for (int kh = 0; kh < 2; ++kh) {
        const int c0 = kh * 8 + quad * 2;
        float4 va = *(const float4*)(xzw + s16 * 64 + ((c0 ^ s16) & 15) * 4);
        float4 vb = *(const float4*)(xzw + s16 * 64 + (((c0 + 1) ^ s16) & 15) * 4);
        uint4v u = {pk2bf(va.x, va.y), pk2bf(va.z, va.w),
                    pk2bf(vb.x, vb.y), pk2bf(vb.z, vb.w)};
        bfr[kh] = __builtin_bit_cast(short8, u);
    }

    __syncthreads();   // C'/D/E' image ready for all waves

    const float* w2f = (const float*)(lds);
    const float* b1f = (const float*)(lds + 4096);
    const float* b2f = (const float*)(lds + 6144);

    const ushort_t* gA   = (const ushort_t*)g_ws;
    const ushort_t* gBlo = (const ushort_t*)(g_ws + BLO_OFF);
    const ushort_t* gBhi = (const ushort_t*)(g_ws + BHI_OFF);
    const int fo = s16 * 32 + quad * 8;

    auto ldA = [&](int w, short8& a00, short8& a10, short8& a01, short8& a11) {
        if (w < 8) {
            const ushort_t* b = gA + w * 1024 + fo;
            a00 = *(const short8*)(b);
            a10 = *(const short8*)(b + 512);
        } else {
            const int off = (w - 8) * 1024 + fo;
            a00 = *(const short8*)(gBlo + off);
            a10 = *(const short8*)(gBlo + off + 512);
            a01 = *(const short8*)(gBhi + off);
            a11 = *(const short8*)(gBhi + off + 512);
        }
    };

    short8 A00[2], A10[2], A01[2] = {}, A11[2] = {};
    ldA(0, A00[0], A10[0], A01[0], A11[0]);

    float lsum = 0.0f;
    #pragma unroll
    for (int w = 0; w < 16; ++w) {
        const int cur = w & 1, nxt = cur ^ 1;
        if (w < 15) ldA(w + 1, A00[nxt], A10[nxt], A01[nxt], A11[nxt]);

        const float4 bi0 = *(const float4*)(b1f + w * 32 + quad * 4);
        const float4 bi1 = *(const float4*)(b1f + w * 32 + 16 + quad * 4);

        f32x4 aE = {bi0.x, bi0.y, bi0.z, bi0.w};
        f32x4 aO = {bi1.x, bi1.y, bi1.z, bi1.w};
        aE = __builtin_amdgcn_mfma_f32_16x16x32_bf16(A00[cur], bfr[0], aE, 0, 0, 0);
        aO = __builtin_amdgcn_mfma_f32_16x16x32_bf16(A10[cur], bfr[0], aO, 0, 0, 0);
        if (w >= 8) {
            aE = __builtin_amdgcn_mfma_f32_16x16x32_bf16(A01[cur], bfr[1], aE, 0, 0, 0);
            aO = __builtin_amdgcn_mfma_f32_16x16x32_bf16(A11[cur], bfr[1], aO, 0, 0, 0);
        }

        // lane owns layer l = 4w+quad, sample s16
        const float r0 = sg(aE[0]), r1 = sg(aE[1]), r2 = sg(aE[2]), r3 = sg(aE[3]);
        const float r4 = sg(aO[0]), r5 = sg(aO[1]), r6 = sg(aO[2]), r7 = sg(aO[3]);

        const int l = 4 * w + quad;
        const float4 m0 = *(const float4*)(w2f + l * 16);
        const float4 m1 = *(const float4*)(w2f + l * 16 + 4);
        const float4 a0 = *(const float4*)(w2f + l * 16 + 8);
        const float4 a1 = *(const float4*)(w2f + l * 16 + 12);
        const float2 bb = *(const float2*)(b2f + l * 2);

        // GEMM2 (tanh affine part pre-folded): two 4-deep partials per output
        float mu0 = bb.x, mu1 = m1.x * r4;
        mu0 = fmaf(m0.x, r0, mu0); mu1 = fmaf(m1.y, r5, mu1);
        mu0 = fmaf(m0.y, r1, mu0); mu1 = fmaf(m1.z, r6, mu1);
        mu0 = fmaf(m0.z, r2, mu0); mu1 = fmaf(m1.w, r7, mu1);
        mu0 = fmaf(m0.w, r3, mu0);
        float mu = mu0 + mu1;
        float al0 = bb.y, al1 = a1.x * r4;
        al0 = fmaf(a0.x, r0, al0); al1 = fmaf(a1.y, r5, al1);
        al0 = fmaf(a0.y, r1, al0); al1 = fmaf(a1.z, r6, al1);
        al0 = fmaf(a0.z, r2, al0); al1 = fmaf(a1.w, r7, al1);
        al0 = fmaf(a0.w, r3, al0);
        float alg = al0 + al1;          // alpha in log2 domain

        int d = l + 1;
        if (w == 15) {                   // compile-time: pad lane handling only here
            const bool pad = (quad == 3);       // l == 63
            alg = pad ? ip1l2 : alg;
            mu  = pad ? ip0 : mu;
            d   = pad ? 0 : d;
        }
        float* pz = xzw + s16 * 64 + ((((d >> 2) ^ s16) & 15) << 2) + (d & 3);
        *pz = fmaf(*pz, EXP2F(alg), mu);
        lsum += alg;
    }

    // ---- coalesced LDS -> global z store ----
    #pragma unroll
    for (int g = 0; g < 4; ++g) {
        const int s_loc = 4 * g + quad;
        const int pc = (s16 ^ s_loc) & 15;
        const float4 v = *(const float4*)(xzw + s_loc * 64 + pc * 4);
        ((float4*)(out + (size_t)sbase * DIMS))[g * 64 + lane] = v;
    }

    // ---- log_det: sum 4 quad-partials per sample, rescale log2 -> ln ----
    {
        float v = lsum;
        int r1 = __builtin_amdgcn_ds_swizzle(__float_as_int(v), 0x401F);  // xor 16
        v += __int_as_float(r1);
        int r2 = __builtin_amdgcn_ds_bpermute((lane ^ 32) << 2, __float_as_int(v));
        v += __int_as_float(r2);
        if (quad == 0)
            out[(size_t)nB * DIMS + sbase + s16] = v * LN2;
    }
}

__global__ __launch_bounds__(TPB, 8) void siaf_main_fb(
        const float* __restrict__ x, const float* __restrict__ ip,
        float* __restrict__ out, int nB) {
    extern __shared__ unsigned char lds[];
    siaf_body(lds, x, ip, out, nB, true);
}

__global__ __launch_bounds__(TPB, 8) void siaf_fused(
        const float* __restrict__ x, const float* __restrict__ ip,
        const float* __restrict__ W1, const float* __restrict__ b1,
        const float* __restrict__ W2, const float* __restrict__ b2,
        float* __restrict__ out, int nB) {
    extern __shared__ unsigned char lds[];
    const int tid  = threadIdx.x;
    const int wv   = tid >> 6, lane = tid & 63;
    const int s16  = lane & 15, quad = lane >> 4;
    const int sbase = blockIdx.x * (WAVES * SPW) + wv * SPW;
    float* xzw = (float*)(lds + XZ_OFF) + wv * (SPW * DIMS);

    // x-stage first (own-block LDS, independent of g_ws): global latency
    // overlaps the prep gather + grid barrier below.
    x_stage(xzw, x, sbase, s16, quad, lane);

    // distributed prep: 1 element/thread, blocks 0..51 participate
    const int gi = blockIdx.x * TPB + tid;
    if (gi < PREP_N) prep_element(gi, W1, b1, W2, b2);

    __threadfence();               // writer-side release (cross-XCD L2 writeback)
    cg::this_grid().sync();        // g_ws image complete, device-visible

    siaf_body(lds, x, ip, out, nB, false);
}

extern "C" void kernel_launch(void* const* d_in, const int* in_sizes, int n_in,
                              void* d_out, int out_size, void* d_ws, size_t ws_size,
                              hipStream_t stream) {
    const float* x  = (const float*)d_in[0];
    const float* ip = (const float*)d_in[1];
    const float* W1 = (const float*)d_in[2];
    const float* b1 = (const float*)d_in[3];
    const float* W2 = (const float*)d_in[4];
    const float* b2 = (const float*)d_in[5];
    float* out = (float*)d_out;
    (void)d_ws; (void)ws_size;              // workspace unused (poison is unconditional)

    const int nB = in_sizes[0] / DIMS;      // 131072
    const int grid = nB / (WAVES * SPW);    // 1024

    (void)hipFuncSetAttribute((const void*)siaf_fused,
                              hipFuncAttributeMaxDynamicSharedMemorySize, LDS_BYTES);
    (void)hipFuncSetAttribute((const void*)siaf_main_fb,
                              hipFuncAttributeMaxDynamicSharedMemorySize, LDS_BYTES);

    // cooperative path requires full-grid co-residency (4 blocks/CU x 256 CU)
    static int coop_ok = -1;
    if (coop_ok < 0) {
        int maxb = 0;
        hipError_t e = hipOccupancyMaxActiveBlocksPerMultiprocessor(
            &maxb, (const void*)siaf_fused, TPB, LDS_BYTES);
        coop_ok = (e == hipSuccess && maxb >= 4) ? 1 : 0;
    }

    bool launched = false;
    if (coop_ok == 1) {
        void* args[] = {(void*)&x, (void*)&ip, (void*)&W1, (void*)&b1,
                        (void*)&W2, (void*)&b2, (void*)&out, (void*)&nB};
        hipError_t e = hipLaunchCooperativeKernel(
            (const void*)siaf_fused, dim3(grid), dim3(TPB), args, LDS_BYTES, stream);
        if (e == hipSuccess) launched = true;
        else coop_ok = 0;
    }
    if (!launched) {
        siaf_prep<<<(PREP_N + 255) / 256, 256, 0, stream>>>(W1, b1, W2, b2);
        siaf_main_fb<<<grid, TPB, LDS_BYTES, stream>>>(x, ip, out, nB);
    }
}